// Round 5
// baseline (626.853 us; speedup 1.0000x reference)
//
#include <hip/hip_runtime.h>

#define N_NODES 50000
#define N_EDGES 800000
#define IN_DIM  1024
#define COUT    127
#define H1      256
#define H2      128
#define LDA     256          // row stride (elements) of xa / x2 / P
#define MBLK    391          // ceil(50000/128)
#define NSTREAM 8192         // agg_epi wave-streams (2048 blocks x 4 waves)
#define LDSS    72           // LDS row stride (elems) for MFMA tiles
#define SCHUNK  49           // scan: elems per thread (1024*49 >= 50000)

typedef __bf16 bf16;
typedef __attribute__((ext_vector_type(8))) __bf16 bf16x8;
typedef __attribute__((ext_vector_type(4))) float floatx4;

__device__ __forceinline__ float bfu_lo(unsigned u) { return __uint_as_float(u << 16); }
__device__ __forceinline__ float bfu_hi(unsigned u) { return __uint_as_float(u & 0xffff0000u); }

// ---- conv1d: h[N,1024] -> xa[:, 0:128] bf16 (col 127 = 0), row stride 256 --
__global__ void conv_kernel(const float* __restrict__ h, const float* __restrict__ w,
                            const float* __restrict__ b, bf16* __restrict__ xa) {
    int n = blockIdx.x;
    int t = threadIdx.x;                           // 0..127
    const float* hr = h + (size_t)n * IN_DIM;
    float r = 0.f;
    if (t < COUT) {
        const float* p = hr + t * 8;               // 32B aligned
        float4 a = *(const float4*)p;
        float4 c = *(const float4*)(p + 4);
        float2 d = *(const float2*)(p + 8);
        float s = b[0];
        s += a.x * w[0] + a.y * w[1] + a.z * w[2] + a.w * w[3];
        s += c.x * w[4] + c.y * w[5] + c.z * w[6] + c.w * w[7];
        s += d.x * w[8] + d.y * w[9];
        r = fmaxf(s, 0.f);
    }
    xa[(size_t)n * LDA + t] = (bf16)r;
}

// ---------------- CSR build ----------------
__global__ void deg_kernel(const int* __restrict__ dst, int* __restrict__ deg) {
    int e = blockIdx.x * blockDim.x + threadIdx.x;
    if (e < N_EDGES) atomicAdd(&deg[dst[e]], 1);
}

// parallel single-kernel scan: each thread owns a 49-elem chunk in registers.
__global__ __launch_bounds__(1024) void scan_kernel(const int* __restrict__ deg,
                                                    int* __restrict__ rowptr,
                                                    int* __restrict__ cursor) {
    int t = threadIdx.x;
    int base = t * SCHUNK;
    int v[SCHUNK];
    int sum = 0;
    #pragma unroll
    for (int i = 0; i < SCHUNK; ++i) {
        int idx = base + i;
        v[i] = (idx < N_NODES) ? deg[idx] : 0;
        sum += v[i];
    }
    __shared__ int wsum[16];
    int lane = t & 63, wid = t >> 6;
    int s = sum;
    #pragma unroll
    for (int off = 1; off < 64; off <<= 1) {
        int q = __shfl_up(s, off);
        if (lane >= off) s += q;
    }
    if (lane == 63) wsum[wid] = s;
    __syncthreads();
    if (t < 16) {
        int ws = wsum[t];
        #pragma unroll
        for (int off = 1; off < 16; off <<= 1) {
            int q = __shfl_up(ws, off);
            if (t >= off) ws += q;
        }
        wsum[t] = ws;
    }
    __syncthreads();
    int excl = ((wid == 0) ? 0 : wsum[wid - 1]) + (s - sum);
    int run = excl;
    #pragma unroll
    for (int i = 0; i < SCHUNK; ++i) {
        int idx = base + i;
        if (idx < N_NODES) { rowptr[idx] = run; cursor[idx] = run; }
        run += v[i];
    }
    if (t == 1023) rowptr[N_NODES] = run;          // == E (tail v[i]=0)
}

__global__ void fill_kernel(const int* __restrict__ src, const int* __restrict__ dst,
                            int* __restrict__ cursor, int* __restrict__ esrc) {
    int e = blockIdx.x * blockDim.x + threadIdx.x;
    if (e < N_EDGES) {
        int d = dst[e];
        int pos = atomicAdd(&cursor[d], 1);
        esrc[pos] = src[e];
    }
}

// ---- mean agg: xa[:, 128:256] = mean of in-neighbor xa[:, 0:128] -----------
// One wave per node; lane loads one uint (2 bf16) -> full 256B row per instr.
__global__ __launch_bounds__(256) void agg_kernel(bf16* __restrict__ xa,
                                                  const int* __restrict__ rowptr,
                                                  const int* __restrict__ esrc) {
    int w = threadIdx.x >> 6, lane = threadIdx.x & 63;
    int n = blockIdx.x * 4 + w;                    // 12500*4 = 50000 exactly
    const unsigned* base = (const unsigned*)xa;    // row = 128 uints
    int s0 = rowptr[n], s1 = rowptr[n + 1];
    float a0 = 0.f, a1 = 0.f;
    int e = s0;
    for (; e + 8 <= s1; e += 8) {
        unsigned u0 = base[(size_t)esrc[e]     * 128 + lane];
        unsigned u1 = base[(size_t)esrc[e + 1] * 128 + lane];
        unsigned u2 = base[(size_t)esrc[e + 2] * 128 + lane];
        unsigned u3 = base[(size_t)esrc[e + 3] * 128 + lane];
        unsigned u4 = base[(size_t)esrc[e + 4] * 128 + lane];
        unsigned u5 = base[(size_t)esrc[e + 5] * 128 + lane];
        unsigned u6 = base[(size_t)esrc[e + 6] * 128 + lane];
        unsigned u7 = base[(size_t)esrc[e + 7] * 128 + lane];
        a0 += ((bfu_lo(u0) + bfu_lo(u1)) + (bfu_lo(u2) + bfu_lo(u3)))
            + ((bfu_lo(u4) + bfu_lo(u5)) + (bfu_lo(u6) + bfu_lo(u7)));
        a1 += ((bfu_hi(u0) + bfu_hi(u1)) + (bfu_hi(u2) + bfu_hi(u3)))
            + ((bfu_hi(u4) + bfu_hi(u5)) + (bfu_hi(u6) + bfu_hi(u7)));
    }
    for (; e < s1; ++e) {
        unsigned u = base[(size_t)esrc[e] * 128 + lane];
        a0 += bfu_lo(u);  a1 += bfu_hi(u);
    }
    float dnm = (float)max(s1 - s0, 1);
    bf16 b0 = (bf16)(a0 / dnm), b1 = (bf16)(a1 / dnm);
    ushort2 pk;
    pk.x = *(unsigned short*)&b0;  pk.y = *(unsigned short*)&b1;
    *(ushort2*)&xa[(size_t)n * LDA + 128 + lane * 2] = pk;
}

// ---- pack both weight matrices to bf16 transposed [n][k] -------------------
// wt1: k<127 -> ws1[k][n]; 128<=k<255 -> wn1[k-128][n]; else 0
// wt2: n<128 -> ws2[k][n]; else wn2[k][n-128]
__global__ void padw_kernel(const float* __restrict__ ws1, const float* __restrict__ wn1,
                            const float* __restrict__ ws2, const float* __restrict__ wn2,
                            bf16* __restrict__ wt1, bf16* __restrict__ wt2) {
    int i = blockIdx.x * blockDim.x + threadIdx.x; // 0 .. 131071
    if (i < 65536) {
        int n = i >> 8, k = i & 255;
        float v = 0.f;
        if (k < COUT)                        v = ws1[k * H1 + n];
        else if (k >= 128 && k < 128 + COUT) v = wn1[(k - 128) * H1 + n];
        wt1[i] = (bf16)v;
    } else {
        int j = i - 65536;
        int n = j >> 8, k = j & 255;
        float v = (n < H2) ? ws2[k * H2 + n] : wn2[k * H2 + (n - H2)];
        wt2[j] = (bf16)v;
    }
}

// ---- MFMA GEMM: out[N,256] = (relu?)(X[N,256] @ W[256,256] (+bias)), bf16 --
// (unchanged from R4 — verified correct, absmax 7.6e-6)
template <bool RELU>
__global__ __launch_bounds__(256) void gemm_mfma(
        const bf16* __restrict__ X, const bf16* __restrict__ WT,
        const float* __restrict__ bias, bf16* __restrict__ out) {
    __shared__ bf16 As[128 * LDSS];
    __shared__ bf16 Bs[64 * LDSS];
    int tid  = threadIdx.x;
    int lane = tid & 63, w = tid >> 6;
    int quad = lane >> 4, l16 = lane & 15;
    int m0 = blockIdx.x * 128;
    int n0 = blockIdx.y * 64;
    floatx4 acc[2][4] = {};

    for (int k0 = 0; k0 < 256; k0 += 64) {
        uint4 av[4], bv[2];
        #pragma unroll
        for (int i = 0; i < 4; ++i) {
            int c = tid + 256 * i;
            int row = c >> 3, col = (c & 7) * 8;
            int gr = m0 + row;
            av[i] = (gr < N_NODES) ? *(const uint4*)(X + (size_t)gr * LDA + k0 + col)
                                   : make_uint4(0u, 0u, 0u, 0u);
        }
        #pragma unroll
        for (int i = 0; i < 2; ++i) {
            int c = tid + 256 * i;
            int row = c >> 3, col = (c & 7) * 8;
            bv[i] = *(const uint4*)(WT + (size_t)(n0 + row) * 256 + k0 + col);
        }
        __syncthreads();
        #pragma unroll
        for (int i = 0; i < 4; ++i) {
            int c = tid + 256 * i;
            int row = c >> 3, col = (c & 7) * 8;
            *(uint4*)&As[row * LDSS + col] = av[i];
        }
        #pragma unroll
        for (int i = 0; i < 2; ++i) {
            int c = tid + 256 * i;
            int row = c >> 3, col = (c & 7) * 8;
            *(uint4*)&Bs[row * LDSS + col] = bv[i];
        }
        __syncthreads();

        #pragma unroll
        for (int ks = 0; ks < 2; ++ks) {
            int kin = ks * 32 + quad * 8;
            bf16x8 a0 = *(const bf16x8*)&As[(w * 32 + l16) * LDSS + kin];
            bf16x8 a1 = *(const bf16x8*)&As[(w * 32 + 16 + l16) * LDSS + kin];
            bf16x8 b0 = *(const bf16x8*)&Bs[(l16) * LDSS + kin];
            bf16x8 b1 = *(const bf16x8*)&Bs[(16 + l16) * LDSS + kin];
            bf16x8 b2 = *(const bf16x8*)&Bs[(32 + l16) * LDSS + kin];
            bf16x8 b3 = *(const bf16x8*)&Bs[(48 + l16) * LDSS + kin];
            acc[0][0] = __builtin_amdgcn_mfma_f32_16x16x32_bf16(a0, b0, acc[0][0], 0, 0, 0);
            acc[0][1] = __builtin_amdgcn_mfma_f32_16x16x32_bf16(a0, b1, acc[0][1], 0, 0, 0);
            acc[0][2] = __builtin_amdgcn_mfma_f32_16x16x32_bf16(a0, b2, acc[0][2], 0, 0, 0);
            acc[0][3] = __builtin_amdgcn_mfma_f32_16x16x32_bf16(a0, b3, acc[0][3], 0, 0, 0);
            acc[1][0] = __builtin_amdgcn_mfma_f32_16x16x32_bf16(a1, b0, acc[1][0], 0, 0, 0);
            acc[1][1] = __builtin_amdgcn_mfma_f32_16x16x32_bf16(a1, b1, acc[1][1], 0, 0, 0);
            acc[1][2] = __builtin_amdgcn_mfma_f32_16x16x32_bf16(a1, b2, acc[1][2], 0, 0, 0);
            acc[1][3] = __builtin_amdgcn_mfma_f32_16x16x32_bf16(a1, b3, acc[1][3], 0, 0, 0);
        }
    }

    float bvv[4] = {};
    if constexpr (RELU) {
        #pragma unroll
        for (int nt = 0; nt < 4; ++nt) bvv[nt] = bias[n0 + nt * 16 + l16];
    }
    #pragma unroll
    for (int mt = 0; mt < 2; ++mt) {
        #pragma unroll
        for (int r = 0; r < 4; ++r) {
            int m = m0 + w * 32 + mt * 16 + quad * 4 + r;
            if (m < N_NODES) {
                #pragma unroll
                for (int nt = 0; nt < 4; ++nt) {
                    float v = acc[mt][nt][r];
                    if constexpr (RELU) v = fmaxf(v + bvv[nt], 0.f);
                    out[(size_t)m * LDA + n0 + nt * 16 + l16] = (bf16)v;
                }
            }
        }
    }
}

// ---- layer-2 aggregate + epilogue + partial pool (wave per node-stream) ----
// P[:, :128] = x2@Ws2 (self), P[:, 128:] = x2@Wn2 (neigh projection).
// y2[n] = relu(P[n,:128] + mean_{src} P[src,128:] + b2); partial[stream] += y2.
__global__ __launch_bounds__(256) void agg_epi_kernel(
        const bf16* __restrict__ P, const int* __restrict__ rowptr,
        const int* __restrict__ esrc, const float* __restrict__ b2,
        float* __restrict__ partial) {
    int w = threadIdx.x >> 6, lane = threadIdx.x & 63;
    int sid = blockIdx.x * 4 + w;                  // 0..NSTREAM-1
    int f0 = lane * 2;
    float bf0 = b2[f0], bf1 = b2[f0 + 1];
    const unsigned* base = (const unsigned*)P;     // row = 128 uints
    float cs0 = 0.f, cs1 = 0.f;
    for (int n = sid; n < N_NODES; n += NSTREAM) {
        int s0 = rowptr[n], s1 = rowptr[n + 1];
        float a0 = 0.f, a1 = 0.f;
        int e = s0;
        for (; e + 8 <= s1; e += 8) {
            unsigned u0 = base[(size_t)esrc[e]     * 128 + 64 + lane];
            unsigned u1 = base[(size_t)esrc[e + 1] * 128 + 64 + lane];
            unsigned u2 = base[(size_t)esrc[e + 2] * 128 + 64 + lane];
            unsigned u3 = base[(size_t)esrc[e + 3] * 128 + 64 + lane];
            unsigned u4 = base[(size_t)esrc[e + 4] * 128 + 64 + lane];
            unsigned u5 = base[(size_t)esrc[e + 5] * 128 + 64 + lane];
            unsigned u6 = base[(size_t)esrc[e + 6] * 128 + 64 + lane];
            unsigned u7 = base[(size_t)esrc[e + 7] * 128 + 64 + lane];
            a0 += ((bfu_lo(u0) + bfu_lo(u1)) + (bfu_lo(u2) + bfu_lo(u3)))
                + ((bfu_lo(u4) + bfu_lo(u5)) + (bfu_lo(u6) + bfu_lo(u7)));
            a1 += ((bfu_hi(u0) + bfu_hi(u1)) + (bfu_hi(u2) + bfu_hi(u3)))
                + ((bfu_hi(u4) + bfu_hi(u5)) + (bfu_hi(u6) + bfu_hi(u7)));
        }
        for (; e < s1; ++e) {
            unsigned u = base[(size_t)esrc[e] * 128 + 64 + lane];
            a0 += bfu_lo(u);  a1 += bfu_hi(u);
        }
        float dnm = (float)max(s1 - s0, 1);
        unsigned us = base[(size_t)n * 128 + lane];
        float y0 = bfu_lo(us) + a0 / dnm + bf0;
        float y1 = bfu_hi(us) + a1 / dnm + bf1;
        cs0 += fmaxf(y0, 0.f);
        cs1 += fmaxf(y1, 0.f);
    }
    float2 o;  o.x = cs0;  o.y = cs1;
    *(float2*)&partial[(size_t)sid * 128 + f0] = o;
}

// ---- reduce partials: hg[f] = sum_s partial[s][f] --------------------------
__global__ __launch_bounds__(256) void reduce_kernel(const float* __restrict__ partial,
                                                     float* __restrict__ hg) {
    int f = blockIdx.x, t = threadIdx.x;
    float s = 0.f;
    for (int i = t; i < NSTREAM; i += 256) s += partial[(size_t)i * 128 + f];
    __shared__ float ls[4];
    #pragma unroll
    for (int off = 32; off >= 1; off >>= 1) s += __shfl_down(s, off);
    if ((t & 63) == 0) ls[t >> 6] = s;
    __syncthreads();
    if (t == 0) hg[f] = (ls[0] + ls[1]) + (ls[2] + ls[3]);
}

// ---------------- mean + MLP head (single block, fp32) ----------------------
__global__ void mlp_kernel(const float* __restrict__ hg,
                           const float* __restrict__ f1w, const float* __restrict__ f1b,
                           const float* __restrict__ f2w, const float* __restrict__ f2b,
                           const float* __restrict__ f3w, const float* __restrict__ f3b,
                           float* __restrict__ out) {
    __shared__ float h0[128], y1[64], y2[32];
    int t = threadIdx.x;
    if (t < 128) h0[t] = hg[t] * (1.0f / N_NODES);
    __syncthreads();
    if (t < 64) {
        float s = f1b[t];
        for (int k = 0; k < 128; ++k) s += h0[k] * f1w[k * 64 + t];
        y1[t] = fmaxf(s, 0.f);
    }
    __syncthreads();
    if (t < 32) {
        float s = f2b[t];
        for (int k = 0; k < 64; ++k) s += y1[k] * f2w[k * 32 + t];
        y2[t] = fmaxf(s, 0.f);
    }
    __syncthreads();
    if (t == 0) {
        float s = f3b[0];
        for (int k = 0; k < 32; ++k) s += y2[k] * f3w[k];
        out[0] = s;
    }
}

extern "C" void kernel_launch(void* const* d_in, const int* in_sizes, int n_in,
                              void* d_out, int out_size, void* d_ws, size_t ws_size,
                              hipStream_t stream) {
    (void)in_sizes; (void)n_in; (void)out_size; (void)ws_size;
    const float* h        = (const float*)d_in[0];
    const int*   src      = (const int*)d_in[1];
    const int*   dst      = (const int*)d_in[2];
    const float* cw       = (const float*)d_in[3];
    const float* cb       = (const float*)d_in[4];
    const float* w_self1  = (const float*)d_in[5];
    const float* w_neigh1 = (const float*)d_in[6];
    const float* b1       = (const float*)d_in[7];
    const float* w_self2  = (const float*)d_in[8];
    const float* w_neigh2 = (const float*)d_in[9];
    const float* b2       = (const float*)d_in[10];
    const float* f1w      = (const float*)d_in[11];
    const float* f1b      = (const float*)d_in[12];
    const float* f2w      = (const float*)d_in[13];
    const float* f2b      = (const float*)d_in[14];
    const float* f3w      = (const float*)d_in[15];
    const float* f3b      = (const float*)d_in[16];
    float* out = (float*)d_out;

    // workspace (bytes, 256-aligned); P overlays xa (xa dead after gemm1)
    char* ws = (char*)d_ws;
    bf16*  xa    = (bf16*) (ws + 0);           // 50048*256*2 = 25,624,576
    bf16*  P     = (bf16*) (ws + 0);           // overlay
    bf16*  x2    = (bf16*) (ws + 25624576);    // 25,624,576
    bf16*  wt1   = (bf16*) (ws + 51249152);    // 131,072
    bf16*  wt2   = (bf16*) (ws + 51380224);    // 131,072
    int*   deg   = (int*)  (ws + 51511296);    // 200,192 (also cursor)
    int*   rowp  = (int*)  (ws + 51711488);    // 200,448
    int*   esrc  = (int*)  (ws + 51911936);    // 3,200,000
    float* part  = (float*)(ws + 55111936);    // 8192*128*4 = 4,194,304
    float* hg    = (float*)(ws + 59306240);    // 512     (total ~59.3 MB)
    int*   cur   = deg;                        // alias: deg dead after scan

    hipMemsetAsync(deg, 0, N_NODES * sizeof(int), stream);

    padw_kernel<<<512, 256, 0, stream>>>(w_self1, w_neigh1, w_self2, w_neigh2, wt1, wt2);
    deg_kernel<<<(N_EDGES + 255) / 256, 256, 0, stream>>>(dst, deg);
    scan_kernel<<<1, 1024, 0, stream>>>(deg, rowp, cur);
    fill_kernel<<<(N_EDGES + 255) / 256, 256, 0, stream>>>(src, dst, cur, esrc);
    conv_kernel<<<N_NODES, 128, 0, stream>>>(h, cw, cb, xa);
    agg_kernel<<<12500, 256, 0, stream>>>(xa, rowp, esrc);
    dim3 g(MBLK, 4);
    gemm_mfma<true><<<g, 256, 0, stream>>>(xa, wt1, b1, x2);
    gemm_mfma<false><<<g, 256, 0, stream>>>(x2, wt2, nullptr, P);
    agg_epi_kernel<<<NSTREAM / 4, 256, 0, stream>>>(P, rowp, esrc, b2, part);
    reduce_kernel<<<128, 256, 0, stream>>>(part, hg);
    mlp_kernel<<<1, 128, 0, stream>>>(hg, f1w, f1b, f2w, f2b, f3w, f3b, out);
}